// Round 15
// baseline (179.955 us; speedup 1.0000x reference)
//
#include <hip/hip_runtime.h>
#include <math.h>

#define B_ 256
#define I_ 512
#define H_ 512
#define BH (B_*H_)
#define NCH 8            // h-chunks for hebbdot partials
#define HCH (H_/NCH)     // 64

typedef float f4v __attribute__((ext_vector_type(4)));

// ws layout (floats):
// [0, 8*BH)        : gate pre-act partials  [ks*4+g][b][k]  (split-K 2)
// [8*BH, 16*BH)    : part[ch][b][k] hebbdot partials

// ---------------------------------------------------------------------------
// K_A: fused (R14 winner): blocks [0,1024) gate GEMM (split-K x2, 32x32
// tile, TK=32, reg-prefetch + LDS dbuf), blocks [1024,3072) hebbdot
// partials. ONLY change vs R14: hebb reads are non-temporal (L1 bypass).
// ---------------------------------------------------------------------------
#define TK 32
#define LDB 34               // padded LDS row stride (floats)
#define TILE_F (TK*LDB)      // 1088 floats per operand buffer
#define NGEMM 1024

__global__ __launch_bounds__(256) void k_dot_gates(
    const float* __restrict__ hebb, const float* __restrict__ h0,
    const float* __restrict__ inputs,
    const float* __restrict__ Wxf, const float* __restrict__ Whf,
    const float* __restrict__ Wxi, const float* __restrict__ Whi,
    const float* __restrict__ Wxo, const float* __restrict__ Who,
    const float* __restrict__ Wxc, const float* __restrict__ w,
    float* __restrict__ pre, float* __restrict__ part) {

    __shared__ float smem[4 * TILE_F];   // 17408 B; aliased by both paths
    int bid = blockIdx.x;
    int tid = threadIdx.x;

    if (bid < NGEMM) {
        // ---------------- gate GEMM path (split-K) ----------------
        int ks = bid & 1;             // 0: inputs@Wx, 1: h0@Wh (or w)
        int m0 = ((bid >> 1) & 7) * 32;
        int n0 = (bid >> 4) * 32;     // [0,2048)
        int g  = n0 >> 9;             // 0=f,1=i,2=o,3=c
        int ko0 = n0 & 511;

        const float* Asrc = ks ? h0 : inputs;
        const float* Bsrc;
        bool wpath = false;
        if (ks == 0) {
            Bsrc = (g == 0) ? Wxf : (g == 1) ? Wxi : (g == 2) ? Wxo : Wxc;
        } else {
            if (g == 3) { Bsrc = w; wpath = true; }
            else Bsrc = (g == 0) ? Whf : (g == 1) ? Whi : Who;
        }

        int row = tid >> 3;          // 0..31
        int c4  = tid & 7;           // float4 index along k (or n for wpath)
        int tx  = tid & 15, ty = tid >> 4;

        float acc[2][2] = {{0.f, 0.f}, {0.f, 0.f}};
        float4 areg, breg;

        auto LOAD = [&](int t) {
            int kb = t * TK;
            areg = *(const float4*)&Asrc[(size_t)(m0 + row) * 512 + kb + c4 * 4];
            if (wpath)
                breg = *(const float4*)&Bsrc[(size_t)(kb + row) * 512 + ko0 + c4 * 4];
            else
                breg = *(const float4*)&Bsrc[(size_t)(ko0 + row) * 512 + kb + c4 * 4];
        };
        auto STORE = [&](int pbuf) {
            float* As = smem + pbuf * 2 * TILE_F;   // [TK][LDB]  (k-major)
            float* Bs = As + TILE_F;
            #pragma unroll
            for (int j = 0; j < 4; ++j)
                As[(c4 * 4 + j) * LDB + row] = ((const float*)&areg)[j];
            if (wpath) {
                #pragma unroll
                for (int j = 0; j < 4; ++j)
                    Bs[row * LDB + c4 * 4 + j] = ((const float*)&breg)[j];
            } else {
                #pragma unroll
                for (int j = 0; j < 4; ++j)
                    Bs[(c4 * 4 + j) * LDB + row] = ((const float*)&breg)[j];
            }
        };

        LOAD(0);
        STORE(0);
        for (int t = 0; t < 16; ++t) {
            __syncthreads();
            if (t < 15) LOAD(t + 1);
            int pb = t & 1;
            const float* As = smem + pb * 2 * TILE_F;
            const float* Bs = As + TILE_F;
            #pragma unroll
            for (int kk = 0; kk < TK; ++kk) {
                float2 a2 = *(const float2*)&As[kk * LDB + ty * 2];
                float2 b2 = *(const float2*)&Bs[kk * LDB + tx * 2];
                acc[0][0] += a2.x * b2.x; acc[0][1] += a2.x * b2.y;
                acc[1][0] += a2.y * b2.x; acc[1][1] += a2.y * b2.y;
            }
            if (t < 15) STORE(pb ^ 1);
        }

        float* pb_out = pre + (size_t)(ks * 4 + g) * BH;
        #pragma unroll
        for (int i = 0; i < 2; ++i) {
            #pragma unroll
            for (int j = 0; j < 2; ++j) {
                int bnum = m0 + ty * 2 + i;
                int ko = ko0 + tx * 2 + j;
                pb_out[(size_t)bnum * H_ + ko] = acc[i][j];
            }
        }
    } else {
        // ---------------- hebbdot path (NT loads) ----------------
        int hbid = bid - NGEMM;
        int b  = hbid >> 3;    // consecutive blocks share b -> contiguous hebb
        int ch = hbid & 7;

        float*  h0s = smem;                    // [64]
        float4* red = (float4*)(smem + 64);    // [256]

        if (tid < HCH) h0s[tid] = h0[b * H_ + ch * HCH + tid];
        __syncthreads();

        const f4v* hbp = (const f4v*)(hebb + ((size_t)b * H_ + (size_t)ch * HCH) * H_);
        int tk = tid & 127;    // float4 column
        int th = tid >> 7;     // 0,1 — split h range
        f4v acc = {0.f, 0.f, 0.f, 0.f};
        #pragma unroll 8
        for (int r = 0; r < 32; ++r) {
            int hh = th * 32 + r;
            float s = h0s[hh];
            f4v vv = __builtin_nontemporal_load(&hbp[(size_t)hh * 128 + tk]);
            acc += s * vv;
        }
        red[tid] = *(float4*)&acc;
        __syncthreads();
        if (tid < 128) {
            float4 a = red[tid], c = red[tid + 128];
            float4 o = make_float4(a.x + c.x, a.y + c.y, a.z + c.z, a.w + c.w);
            ((float4*)(part + ((size_t)ch * B_ + b) * H_))[tid] = o;
        }
    }
}

// ---------------------------------------------------------------------------
// K_B: finalize + update merged (R14 winner, unchanged). 2048 blocks,
// REVERSE slab order (L3-warm tail first).
// ---------------------------------------------------------------------------
__global__ __launch_bounds__(256) void k_updatev(
    const float* __restrict__ hebb, const float* __restrict__ h0,
    const float* __restrict__ pre, const float* __restrict__ part,
    const float* __restrict__ c0in, const float* __restrict__ alpha,
    const float* __restrict__ bxf, const float* __restrict__ bhf,
    const float* __restrict__ bxi, const float* __restrict__ bhi,
    const float* __restrict__ bxo, const float* __restrict__ bho,
    const float* __restrict__ bxc,
    const float* __restrict__ Wmod, const float* __restrict__ bmod,
    const float* __restrict__ Wfan, const float* __restrict__ bfan,
    float* __restrict__ out) {

    __shared__ float vsh[512] __attribute__((aligned(16)));
    __shared__ float h0s[64];
    __shared__ float red[4];
    __shared__ float myeta_sh;

    int rb = 2047 - (int)blockIdx.x;    // reverse dispatch -> reverse memory
    int b  = rb >> 3;
    int ch = rb & 7;
    int t  = threadIdx.x;

    // ---- phase 1: v[b,:] (redundant per block) ----
    float c2r[2], ep = 0.f;
    #pragma unroll
    for (int s = 0; s < 2; ++s) {
        int k = t + s * 256;
        float dot = 0.f;
        #pragma unroll
        for (int c = 0; c < NCH; ++c) dot += part[((size_t)c * B_ + b) * H_ + k];
        size_t off = (size_t)b * H_ + k;
        float pf = pre[0 * BH + off] + pre[4 * BH + off] + bxf[k] + bhf[k];
        float pi = pre[1 * BH + off] + pre[5 * BH + off] + bxi[k] + bhi[k];
        float po = pre[2 * BH + off] + pre[6 * BH + off] + bxo[k] + bho[k];
        float pc = pre[3 * BH + off] + pre[7 * BH + off] + bxc[k];
        float c2 = tanhf(pc + alpha[k] * dot);
        float fg = 1.f / (1.f + expf(-pf));
        float ig = 1.f / (1.f + expf(-pi));
        float og = 1.f / (1.f + expf(-po));
        float cell = fg * c0in[off] + ig * c2;
        float ha = og * tanhf(cell);
        if (ch == 0) {
            out[off] = ha;                 // hactiv
            out[BH + off] = cell;          // cell
        }
        c2r[s] = c2;
        ep += ha * Wmod[k];
    }
    #pragma unroll
    for (int o = 32; o > 0; o >>= 1) ep += __shfl_down(ep, o, 64);
    int wid = t >> 6, lane = t & 63;
    if (lane == 0) red[wid] = ep;
    if (t < 64) h0s[t] = h0[(size_t)b * H_ + ch * 64 + t];
    __syncthreads();
    if (t == 0)
        myeta_sh = tanhf(red[0] + red[1] + red[2] + red[3] + bmod[0]);
    __syncthreads();
    float myeta = myeta_sh;
    #pragma unroll
    for (int s = 0; s < 2; ++s) {
        int k = t + s * 256;
        vsh[k] = (myeta * Wfan[k] + bfan[k]) * c2r[s];
    }
    __syncthreads();

    // ---- phase 2: update 64-row slab, plain loads (L3-warm) + NT stores ----
    int c4 = t & 127;                   // float4 column quad
    int rg = t >> 7;                    // 0,1
    const float4* gin  = (const float4*)(hebb + (size_t)(b * H_ + ch * 64) * H_) + c4;
    f4v*          gout = (f4v*)(out + 2 * BH + (size_t)(b * H_ + ch * 64) * H_) + c4;
    f4v vq = *(const f4v*)&vsh[c4 * 4];
    #pragma unroll 8
    for (int i = 0; i < 32; ++i) {
        int row = i * 2 + rg;           // 0..63
        float u = h0s[row];
        float4 hb4 = gin[(size_t)row * 128];
        f4v r;
        r.x = fminf(fmaxf(hb4.x + u * vq.x, -2.f), 2.f);
        r.y = fminf(fmaxf(hb4.y + u * vq.y, -2.f), 2.f);
        r.z = fminf(fmaxf(hb4.z + u * vq.z, -2.f), 2.f);
        r.w = fminf(fmaxf(hb4.w + u * vq.w, -2.f), 2.f);
        __builtin_nontemporal_store(r, gout + (size_t)row * 128);
    }
}

// ---------------------------------------------------------------------------
extern "C" void kernel_launch(void* const* d_in, const int* in_sizes, int n_in,
                              void* d_out, int out_size, void* d_ws, size_t ws_size,
                              hipStream_t stream) {
    const float* inputs = (const float*)d_in[0];
    const float* h0     = (const float*)d_in[1];
    const float* c0     = (const float*)d_in[2];
    const float* hebb   = (const float*)d_in[3];
    const float* w      = (const float*)d_in[4];
    const float* alpha  = (const float*)d_in[5];
    const float* Wxf = (const float*)d_in[6];  const float* bxf = (const float*)d_in[7];
    const float* Whf = (const float*)d_in[8];  const float* bhf = (const float*)d_in[9];
    const float* Wxi = (const float*)d_in[10]; const float* bxi = (const float*)d_in[11];
    const float* Whi = (const float*)d_in[12]; const float* bhi = (const float*)d_in[13];
    const float* Wxo = (const float*)d_in[14]; const float* bxo = (const float*)d_in[15];
    const float* Who = (const float*)d_in[16]; const float* bho = (const float*)d_in[17];
    const float* Wxc = (const float*)d_in[18]; const float* bxc = (const float*)d_in[19];
    const float* Wmod = (const float*)d_in[20]; const float* bmod = (const float*)d_in[21];
    const float* Wfan = (const float*)d_in[22]; const float* bfan = (const float*)d_in[23];

    float* out = (float*)d_out;
    float* ws  = (float*)d_ws;
    float* pre  = ws;                  // 8*BH (split-K partials, no bias)
    float* part = ws + 8 * BH;         // 8*BH

    // 1) fused: hebbdot NT stream + latency-tolerant scalar split-K GEMM
    k_dot_gates<<<NGEMM + B_ * NCH, 256, 0, stream>>>(
        hebb, h0, inputs,
        Wxf, Whf, Wxi, Whi, Wxo, Who, Wxc, w, pre, part);
    // 2) finalize + update merged (reverse slab order, NT stores)
    k_updatev<<<2048, 256, 0, stream>>>(
        hebb, h0, pre, part, c0, alpha,
        bxf, bhf, bxi, bhi, bxo, bho, bxc,
        Wmod, bmod, Wfan, bfan, out);
}

// Round 16
// 177.056 us; speedup vs baseline: 1.0164x; 1.0164x over previous
//
#include <hip/hip_runtime.h>
#include <math.h>

#define B_ 256
#define I_ 512
#define H_ 512
#define BH (B_*H_)
#define NCH 8            // h-chunks for hebbdot partials
#define HCH (H_/NCH)     // 64

typedef float f4v __attribute__((ext_vector_type(4)));

// ws layout (floats):
// [0, 8*BH)        : gate pre-act partials  [ks*4+g][b][k]  (split-K 2)
// [8*BH, 16*BH)    : part[ch][b][k] hebbdot partials

// ---------------------------------------------------------------------------
// K_A: fused (R15): blocks [0,1024) gate GEMM (split-K x2, 32x32 tile,
// TK=32, reg-prefetch + LDS dbuf), blocks [1024,3072) hebbdot partials with
// NT loads (L1/L2-bypass; hits the L3 populated by last replay's updatev).
// ---------------------------------------------------------------------------
#define TK 32
#define LDB 34               // padded LDS row stride (floats)
#define TILE_F (TK*LDB)      // 1088 floats per operand buffer
#define NGEMM 1024

__global__ __launch_bounds__(256) void k_dot_gates(
    const float* __restrict__ hebb, const float* __restrict__ h0,
    const float* __restrict__ inputs,
    const float* __restrict__ Wxf, const float* __restrict__ Whf,
    const float* __restrict__ Wxi, const float* __restrict__ Whi,
    const float* __restrict__ Wxo, const float* __restrict__ Who,
    const float* __restrict__ Wxc, const float* __restrict__ w,
    float* __restrict__ pre, float* __restrict__ part) {

    __shared__ float smem[4 * TILE_F];   // 17408 B; aliased by both paths
    int bid = blockIdx.x;
    int tid = threadIdx.x;

    if (bid < NGEMM) {
        // ---------------- gate GEMM path (split-K) ----------------
        int ks = bid & 1;             // 0: inputs@Wx, 1: h0@Wh (or w)
        int m0 = ((bid >> 1) & 7) * 32;
        int n0 = (bid >> 4) * 32;     // [0,2048)
        int g  = n0 >> 9;             // 0=f,1=i,2=o,3=c
        int ko0 = n0 & 511;

        const float* Asrc = ks ? h0 : inputs;
        const float* Bsrc;
        bool wpath = false;
        if (ks == 0) {
            Bsrc = (g == 0) ? Wxf : (g == 1) ? Wxi : (g == 2) ? Wxo : Wxc;
        } else {
            if (g == 3) { Bsrc = w; wpath = true; }
            else Bsrc = (g == 0) ? Whf : (g == 1) ? Whi : Who;
        }

        int row = tid >> 3;          // 0..31
        int c4  = tid & 7;           // float4 index along k (or n for wpath)
        int tx  = tid & 15, ty = tid >> 4;

        float acc[2][2] = {{0.f, 0.f}, {0.f, 0.f}};
        float4 areg, breg;

        auto LOAD = [&](int t) {
            int kb = t * TK;
            areg = *(const float4*)&Asrc[(size_t)(m0 + row) * 512 + kb + c4 * 4];
            if (wpath)
                breg = *(const float4*)&Bsrc[(size_t)(kb + row) * 512 + ko0 + c4 * 4];
            else
                breg = *(const float4*)&Bsrc[(size_t)(ko0 + row) * 512 + kb + c4 * 4];
        };
        auto STORE = [&](int pbuf) {
            float* As = smem + pbuf * 2 * TILE_F;   // [TK][LDB]  (k-major)
            float* Bs = As + TILE_F;
            #pragma unroll
            for (int j = 0; j < 4; ++j)
                As[(c4 * 4 + j) * LDB + row] = ((const float*)&areg)[j];
            if (wpath) {
                #pragma unroll
                for (int j = 0; j < 4; ++j)
                    Bs[row * LDB + c4 * 4 + j] = ((const float*)&breg)[j];
            } else {
                #pragma unroll
                for (int j = 0; j < 4; ++j)
                    Bs[(c4 * 4 + j) * LDB + row] = ((const float*)&breg)[j];
            }
        };

        LOAD(0);
        STORE(0);
        for (int t = 0; t < 16; ++t) {
            __syncthreads();
            if (t < 15) LOAD(t + 1);
            int pb = t & 1;
            const float* As = smem + pb * 2 * TILE_F;
            const float* Bs = As + TILE_F;
            #pragma unroll
            for (int kk = 0; kk < TK; ++kk) {
                float2 a2 = *(const float2*)&As[kk * LDB + ty * 2];
                float2 b2 = *(const float2*)&Bs[kk * LDB + tx * 2];
                acc[0][0] += a2.x * b2.x; acc[0][1] += a2.x * b2.y;
                acc[1][0] += a2.y * b2.x; acc[1][1] += a2.y * b2.y;
            }
            if (t < 15) STORE(pb ^ 1);
        }

        float* pb_out = pre + (size_t)(ks * 4 + g) * BH;
        #pragma unroll
        for (int i = 0; i < 2; ++i) {
            #pragma unroll
            for (int j = 0; j < 2; ++j) {
                int bnum = m0 + ty * 2 + i;
                int ko = ko0 + tx * 2 + j;
                pb_out[(size_t)bnum * H_ + ko] = acc[i][j];
            }
        }
    } else {
        // ---------------- hebbdot path (NT loads) ----------------
        int hbid = bid - NGEMM;
        int b  = hbid >> 3;    // consecutive blocks share b -> contiguous hebb
        int ch = hbid & 7;

        float*  h0s = smem;                    // [64]
        float4* red = (float4*)(smem + 64);    // [256]

        if (tid < HCH) h0s[tid] = h0[b * H_ + ch * HCH + tid];
        __syncthreads();

        const f4v* hbp = (const f4v*)(hebb + ((size_t)b * H_ + (size_t)ch * HCH) * H_);
        int tk = tid & 127;    // float4 column
        int th = tid >> 7;     // 0,1 — split h range
        f4v acc = {0.f, 0.f, 0.f, 0.f};
        #pragma unroll 8
        for (int r = 0; r < 32; ++r) {
            int hh = th * 32 + r;
            float s = h0s[hh];
            f4v vv = __builtin_nontemporal_load(&hbp[(size_t)hh * 128 + tk]);
            acc += s * vv;
        }
        red[tid] = *(float4*)&acc;
        __syncthreads();
        if (tid < 128) {
            float4 a = red[tid], c = red[tid + 128];
            float4 o = make_float4(a.x + c.x, a.y + c.y, a.z + c.z, a.w + c.w);
            ((float4*)(part + ((size_t)ch * B_ + b) * H_))[tid] = o;
        }
    }
}

// ---------------------------------------------------------------------------
// K_B: finalize + update merged. 2048 blocks, REVERSE slab order.
// ONLY change vs R15: phase 2 loads batched 8-deep (8x MLP on the cold,
// L3-repopulating read). Plain loads (repopulate L3 for next replay's NT
// hebbdot) + NT stores.
// ---------------------------------------------------------------------------
__global__ __launch_bounds__(256) void k_updatev(
    const float* __restrict__ hebb, const float* __restrict__ h0,
    const float* __restrict__ pre, const float* __restrict__ part,
    const float* __restrict__ c0in, const float* __restrict__ alpha,
    const float* __restrict__ bxf, const float* __restrict__ bhf,
    const float* __restrict__ bxi, const float* __restrict__ bhi,
    const float* __restrict__ bxo, const float* __restrict__ bho,
    const float* __restrict__ bxc,
    const float* __restrict__ Wmod, const float* __restrict__ bmod,
    const float* __restrict__ Wfan, const float* __restrict__ bfan,
    float* __restrict__ out) {

    __shared__ float vsh[512] __attribute__((aligned(16)));
    __shared__ float h0s[64];
    __shared__ float red[4];
    __shared__ float myeta_sh;

    int rb = 2047 - (int)blockIdx.x;    // reverse dispatch -> reverse memory
    int b  = rb >> 3;
    int ch = rb & 7;
    int t  = threadIdx.x;

    // ---- phase 1: v[b,:] (redundant per block) ----
    float c2r[2], ep = 0.f;
    #pragma unroll
    for (int s = 0; s < 2; ++s) {
        int k = t + s * 256;
        float dot = 0.f;
        #pragma unroll
        for (int c = 0; c < NCH; ++c) dot += part[((size_t)c * B_ + b) * H_ + k];
        size_t off = (size_t)b * H_ + k;
        float pf = pre[0 * BH + off] + pre[4 * BH + off] + bxf[k] + bhf[k];
        float pi = pre[1 * BH + off] + pre[5 * BH + off] + bxi[k] + bhi[k];
        float po = pre[2 * BH + off] + pre[6 * BH + off] + bxo[k] + bho[k];
        float pc = pre[3 * BH + off] + pre[7 * BH + off] + bxc[k];
        float c2 = tanhf(pc + alpha[k] * dot);
        float fg = 1.f / (1.f + expf(-pf));
        float ig = 1.f / (1.f + expf(-pi));
        float og = 1.f / (1.f + expf(-po));
        float cell = fg * c0in[off] + ig * c2;
        float ha = og * tanhf(cell);
        if (ch == 0) {
            out[off] = ha;                 // hactiv
            out[BH + off] = cell;          // cell
        }
        c2r[s] = c2;
        ep += ha * Wmod[k];
    }
    #pragma unroll
    for (int o = 32; o > 0; o >>= 1) ep += __shfl_down(ep, o, 64);
    int wid = t >> 6, lane = t & 63;
    if (lane == 0) red[wid] = ep;
    if (t < 64) h0s[t] = h0[(size_t)b * H_ + ch * 64 + t];
    __syncthreads();
    if (t == 0)
        myeta_sh = tanhf(red[0] + red[1] + red[2] + red[3] + bmod[0]);
    __syncthreads();
    float myeta = myeta_sh;
    #pragma unroll
    for (int s = 0; s < 2; ++s) {
        int k = t + s * 256;
        vsh[k] = (myeta * Wfan[k] + bfan[k]) * c2r[s];
    }
    __syncthreads();

    // ---- phase 2: update 64-row slab, loads batched 8-deep + NT stores ----
    int c4 = t & 127;                   // float4 column quad
    int rg = t >> 7;                    // 0,1
    const float4* gin  = (const float4*)(hebb + (size_t)(b * H_ + ch * 64) * H_) + c4;
    f4v*          gout = (f4v*)(out + 2 * BH + (size_t)(b * H_ + ch * 64) * H_) + c4;
    f4v vq = *(const f4v*)&vsh[c4 * 4];
    #pragma unroll
    for (int grp = 0; grp < 4; ++grp) {
        float4 hb[8];
        #pragma unroll
        for (int j = 0; j < 8; ++j) {
            int row = (grp * 8 + j) * 2 + rg;
            hb[j] = gin[(size_t)row * 128];
        }
        #pragma unroll
        for (int j = 0; j < 8; ++j) {
            int row = (grp * 8 + j) * 2 + rg;
            float u = h0s[row];
            f4v r;
            r.x = fminf(fmaxf(hb[j].x + u * vq.x, -2.f), 2.f);
            r.y = fminf(fmaxf(hb[j].y + u * vq.y, -2.f), 2.f);
            r.z = fminf(fmaxf(hb[j].z + u * vq.z, -2.f), 2.f);
            r.w = fminf(fmaxf(hb[j].w + u * vq.w, -2.f), 2.f);
            __builtin_nontemporal_store(r, gout + (size_t)row * 128);
        }
    }
}

// ---------------------------------------------------------------------------
extern "C" void kernel_launch(void* const* d_in, const int* in_sizes, int n_in,
                              void* d_out, int out_size, void* d_ws, size_t ws_size,
                              hipStream_t stream) {
    const float* inputs = (const float*)d_in[0];
    const float* h0     = (const float*)d_in[1];
    const float* c0     = (const float*)d_in[2];
    const float* hebb   = (const float*)d_in[3];
    const float* w      = (const float*)d_in[4];
    const float* alpha  = (const float*)d_in[5];
    const float* Wxf = (const float*)d_in[6];  const float* bxf = (const float*)d_in[7];
    const float* Whf = (const float*)d_in[8];  const float* bhf = (const float*)d_in[9];
    const float* Wxi = (const float*)d_in[10]; const float* bxi = (const float*)d_in[11];
    const float* Whi = (const float*)d_in[12]; const float* bhi = (const float*)d_in[13];
    const float* Wxo = (const float*)d_in[14]; const float* bxo = (const float*)d_in[15];
    const float* Who = (const float*)d_in[16]; const float* bho = (const float*)d_in[17];
    const float* Wxc = (const float*)d_in[18]; const float* bxc = (const float*)d_in[19];
    const float* Wmod = (const float*)d_in[20]; const float* bmod = (const float*)d_in[21];
    const float* Wfan = (const float*)d_in[22]; const float* bfan = (const float*)d_in[23];

    float* out = (float*)d_out;
    float* ws  = (float*)d_ws;
    float* pre  = ws;                  // 8*BH (split-K partials, no bias)
    float* part = ws + 8 * BH;         // 8*BH

    // 1) fused: hebbdot NT stream (L3-hit fast path) + scalar split-K GEMM
    k_dot_gates<<<NGEMM + B_ * NCH, 256, 0, stream>>>(
        hebb, h0, inputs,
        Wxf, Whf, Wxi, Whi, Wxo, Who, Wxc, w, pre, part);
    // 2) finalize + update merged (reverse slabs, 8-deep loads, NT stores)
    k_updatev<<<2048, 256, 0, stream>>>(
        hebb, h0, pre, part, c0, alpha,
        bxf, bhf, bxi, bhi, bxo, bho, bxc,
        Wmod, bmod, Wfan, bfan, out);
}

// Round 17
// 161.413 us; speedup vs baseline: 1.1149x; 1.0969x over previous
//
#include <hip/hip_runtime.h>
#include <math.h>

#define B_ 256
#define I_ 512
#define H_ 512
#define BH (B_*H_)
#define NCH 8            // h-chunks for hebbdot partials
#define HCH (H_/NCH)     // 64

typedef float f4v __attribute__((ext_vector_type(4)));

// ws layout (floats):
// [0, 8*BH)        : gate pre-act partials  [ks*4+g][b][k]  (split-K 2)
// [8*BH, 16*BH)    : part[ch][b][k] hebbdot partials

// ---------------------------------------------------------------------------
// K_A: fused (R14 winner, PLAIN hebbdot loads): blocks [0,1024) gate GEMM
// (split-K x2, 32x32 tile, TK=32, reg-prefetch + LDS dbuf), blocks
// [1024,3072) hebbdot partials. Plain loads re-populate L3 so k_updatev's
// re-read runs warm (the R14 steady state, 161 us best).
// ---------------------------------------------------------------------------
#define TK 32
#define LDB 34               // padded LDS row stride (floats)
#define TILE_F (TK*LDB)      // 1088 floats per operand buffer
#define NGEMM 1024

__global__ __launch_bounds__(256) void k_dot_gates(
    const float* __restrict__ hebb, const float* __restrict__ h0,
    const float* __restrict__ inputs,
    const float* __restrict__ Wxf, const float* __restrict__ Whf,
    const float* __restrict__ Wxi, const float* __restrict__ Whi,
    const float* __restrict__ Wxo, const float* __restrict__ Who,
    const float* __restrict__ Wxc, const float* __restrict__ w,
    float* __restrict__ pre, float* __restrict__ part) {

    __shared__ float smem[4 * TILE_F];   // 17408 B; aliased by both paths
    int bid = blockIdx.x;
    int tid = threadIdx.x;

    if (bid < NGEMM) {
        // ---------------- gate GEMM path (split-K) ----------------
        int ks = bid & 1;             // 0: inputs@Wx, 1: h0@Wh (or w)
        int m0 = ((bid >> 1) & 7) * 32;
        int n0 = (bid >> 4) * 32;     // [0,2048)
        int g  = n0 >> 9;             // 0=f,1=i,2=o,3=c
        int ko0 = n0 & 511;

        const float* Asrc = ks ? h0 : inputs;
        const float* Bsrc;
        bool wpath = false;
        if (ks == 0) {
            Bsrc = (g == 0) ? Wxf : (g == 1) ? Wxi : (g == 2) ? Wxo : Wxc;
        } else {
            if (g == 3) { Bsrc = w; wpath = true; }
            else Bsrc = (g == 0) ? Whf : (g == 1) ? Whi : Who;
        }

        int row = tid >> 3;          // 0..31
        int c4  = tid & 7;           // float4 index along k (or n for wpath)
        int tx  = tid & 15, ty = tid >> 4;

        float acc[2][2] = {{0.f, 0.f}, {0.f, 0.f}};
        float4 areg, breg;

        auto LOAD = [&](int t) {
            int kb = t * TK;
            areg = *(const float4*)&Asrc[(size_t)(m0 + row) * 512 + kb + c4 * 4];
            if (wpath)
                breg = *(const float4*)&Bsrc[(size_t)(kb + row) * 512 + ko0 + c4 * 4];
            else
                breg = *(const float4*)&Bsrc[(size_t)(ko0 + row) * 512 + kb + c4 * 4];
        };
        auto STORE = [&](int pbuf) {
            float* As = smem + pbuf * 2 * TILE_F;   // [TK][LDB]  (k-major)
            float* Bs = As + TILE_F;
            #pragma unroll
            for (int j = 0; j < 4; ++j)
                As[(c4 * 4 + j) * LDB + row] = ((const float*)&areg)[j];
            if (wpath) {
                #pragma unroll
                for (int j = 0; j < 4; ++j)
                    Bs[row * LDB + c4 * 4 + j] = ((const float*)&breg)[j];
            } else {
                #pragma unroll
                for (int j = 0; j < 4; ++j)
                    Bs[(c4 * 4 + j) * LDB + row] = ((const float*)&breg)[j];
            }
        };

        LOAD(0);
        STORE(0);
        for (int t = 0; t < 16; ++t) {
            __syncthreads();
            if (t < 15) LOAD(t + 1);
            int pb = t & 1;
            const float* As = smem + pb * 2 * TILE_F;
            const float* Bs = As + TILE_F;
            #pragma unroll
            for (int kk = 0; kk < TK; ++kk) {
                float2 a2 = *(const float2*)&As[kk * LDB + ty * 2];
                float2 b2 = *(const float2*)&Bs[kk * LDB + tx * 2];
                acc[0][0] += a2.x * b2.x; acc[0][1] += a2.x * b2.y;
                acc[1][0] += a2.y * b2.x; acc[1][1] += a2.y * b2.y;
            }
            if (t < 15) STORE(pb ^ 1);
        }

        float* pb_out = pre + (size_t)(ks * 4 + g) * BH;
        #pragma unroll
        for (int i = 0; i < 2; ++i) {
            #pragma unroll
            for (int j = 0; j < 2; ++j) {
                int bnum = m0 + ty * 2 + i;
                int ko = ko0 + tx * 2 + j;
                pb_out[(size_t)bnum * H_ + ko] = acc[i][j];
            }
        }
    } else {
        // ---------------- hebbdot path (plain loads, L3-allocating) --------
        int hbid = bid - NGEMM;
        int b  = hbid >> 3;    // consecutive blocks share b -> contiguous hebb
        int ch = hbid & 7;

        float*  h0s = smem;                    // [64]
        float4* red = (float4*)(smem + 64);    // [256]

        if (tid < HCH) h0s[tid] = h0[b * H_ + ch * HCH + tid];
        __syncthreads();

        const float4* hbp = (const float4*)(hebb + ((size_t)b * H_ + (size_t)ch * HCH) * H_);
        int tk = tid & 127;    // float4 column
        int th = tid >> 7;     // 0,1 — split h range
        float4 acc = make_float4(0.f, 0.f, 0.f, 0.f);
        #pragma unroll 8
        for (int r = 0; r < 32; ++r) {
            int hh = th * 32 + r;
            float s = h0s[hh];
            float4 vv = hbp[(size_t)hh * 128 + tk];
            acc.x += s * vv.x; acc.y += s * vv.y;
            acc.z += s * vv.z; acc.w += s * vv.w;
        }
        red[tid] = acc;
        __syncthreads();
        if (tid < 128) {
            float4 a = red[tid], c = red[tid + 128];
            float4 o = make_float4(a.x + c.x, a.y + c.y, a.z + c.z, a.w + c.w);
            ((float4*)(part + ((size_t)ch * B_ + b) * H_))[tid] = o;
        }
    }
}

// ---------------------------------------------------------------------------
// K_B: finalize + update merged (R16 batched variant, proven). 2048 blocks,
// REVERSE slab order (L3-warm tail first). Phase 1: redundant v[b,:];
// phase 2: 8-deep batched plain loads (repopulate L3) + NT stores.
// ---------------------------------------------------------------------------
__global__ __launch_bounds__(256) void k_updatev(
    const float* __restrict__ hebb, const float* __restrict__ h0,
    const float* __restrict__ pre, const float* __restrict__ part,
    const float* __restrict__ c0in, const float* __restrict__ alpha,
    const float* __restrict__ bxf, const float* __restrict__ bhf,
    const float* __restrict__ bxi, const float* __restrict__ bhi,
    const float* __restrict__ bxo, const float* __restrict__ bho,
    const float* __restrict__ bxc,
    const float* __restrict__ Wmod, const float* __restrict__ bmod,
    const float* __restrict__ Wfan, const float* __restrict__ bfan,
    float* __restrict__ out) {

    __shared__ float vsh[512] __attribute__((aligned(16)));
    __shared__ float h0s[64];
    __shared__ float red[4];
    __shared__ float myeta_sh;

    int rb = 2047 - (int)blockIdx.x;    // reverse dispatch -> reverse memory
    int b  = rb >> 3;
    int ch = rb & 7;
    int t  = threadIdx.x;

    // ---- phase 1: v[b,:] (redundant per block) ----
    float c2r[2], ep = 0.f;
    #pragma unroll
    for (int s = 0; s < 2; ++s) {
        int k = t + s * 256;
        float dot = 0.f;
        #pragma unroll
        for (int c = 0; c < NCH; ++c) dot += part[((size_t)c * B_ + b) * H_ + k];
        size_t off = (size_t)b * H_ + k;
        float pf = pre[0 * BH + off] + pre[4 * BH + off] + bxf[k] + bhf[k];
        float pi = pre[1 * BH + off] + pre[5 * BH + off] + bxi[k] + bhi[k];
        float po = pre[2 * BH + off] + pre[6 * BH + off] + bxo[k] + bho[k];
        float pc = pre[3 * BH + off] + pre[7 * BH + off] + bxc[k];
        float c2 = tanhf(pc + alpha[k] * dot);
        float fg = 1.f / (1.f + expf(-pf));
        float ig = 1.f / (1.f + expf(-pi));
        float og = 1.f / (1.f + expf(-po));
        float cell = fg * c0in[off] + ig * c2;
        float ha = og * tanhf(cell);
        if (ch == 0) {
            out[off] = ha;                 // hactiv
            out[BH + off] = cell;          // cell
        }
        c2r[s] = c2;
        ep += ha * Wmod[k];
    }
    #pragma unroll
    for (int o = 32; o > 0; o >>= 1) ep += __shfl_down(ep, o, 64);
    int wid = t >> 6, lane = t & 63;
    if (lane == 0) red[wid] = ep;
    if (t < 64) h0s[t] = h0[(size_t)b * H_ + ch * 64 + t];
    __syncthreads();
    if (t == 0)
        myeta_sh = tanhf(red[0] + red[1] + red[2] + red[3] + bmod[0]);
    __syncthreads();
    float myeta = myeta_sh;
    #pragma unroll
    for (int s = 0; s < 2; ++s) {
        int k = t + s * 256;
        vsh[k] = (myeta * Wfan[k] + bfan[k]) * c2r[s];
    }
    __syncthreads();

    // ---- phase 2: update 64-row slab, 8-deep batched loads + NT stores ----
    int c4 = t & 127;                   // float4 column quad
    int rg = t >> 7;                    // 0,1
    const float4* gin  = (const float4*)(hebb + (size_t)(b * H_ + ch * 64) * H_) + c4;
    f4v*          gout = (f4v*)(out + 2 * BH + (size_t)(b * H_ + ch * 64) * H_) + c4;
    f4v vq = *(const f4v*)&vsh[c4 * 4];
    #pragma unroll
    for (int grp = 0; grp < 4; ++grp) {
        float4 hb[8];
        #pragma unroll
        for (int j = 0; j < 8; ++j) {
            int row = (grp * 8 + j) * 2 + rg;
            hb[j] = gin[(size_t)row * 128];
        }
        #pragma unroll
        for (int j = 0; j < 8; ++j) {
            int row = (grp * 8 + j) * 2 + rg;
            float u = h0s[row];
            f4v r;
            r.x = fminf(fmaxf(hb[j].x + u * vq.x, -2.f), 2.f);
            r.y = fminf(fmaxf(hb[j].y + u * vq.y, -2.f), 2.f);
            r.z = fminf(fmaxf(hb[j].z + u * vq.z, -2.f), 2.f);
            r.w = fminf(fmaxf(hb[j].w + u * vq.w, -2.f), 2.f);
            __builtin_nontemporal_store(r, gout + (size_t)row * 128);
        }
    }
}

// ---------------------------------------------------------------------------
extern "C" void kernel_launch(void* const* d_in, const int* in_sizes, int n_in,
                              void* d_out, int out_size, void* d_ws, size_t ws_size,
                              hipStream_t stream) {
    const float* inputs = (const float*)d_in[0];
    const float* h0     = (const float*)d_in[1];
    const float* c0     = (const float*)d_in[2];
    const float* hebb   = (const float*)d_in[3];
    const float* w      = (const float*)d_in[4];
    const float* alpha  = (const float*)d_in[5];
    const float* Wxf = (const float*)d_in[6];  const float* bxf = (const float*)d_in[7];
    const float* Whf = (const float*)d_in[8];  const float* bhf = (const float*)d_in[9];
    const float* Wxi = (const float*)d_in[10]; const float* bxi = (const float*)d_in[11];
    const float* Whi = (const float*)d_in[12]; const float* bhi = (const float*)d_in[13];
    const float* Wxo = (const float*)d_in[14]; const float* bxo = (const float*)d_in[15];
    const float* Who = (const float*)d_in[16]; const float* bho = (const float*)d_in[17];
    const float* Wxc = (const float*)d_in[18]; const float* bxc = (const float*)d_in[19];
    const float* Wmod = (const float*)d_in[20]; const float* bmod = (const float*)d_in[21];
    const float* Wfan = (const float*)d_in[22]; const float* bfan = (const float*)d_in[23];

    float* out = (float*)d_out;
    float* ws  = (float*)d_ws;
    float* pre  = ws;                  // 8*BH (split-K partials, no bias)
    float* part = ws + 8 * BH;         // 8*BH

    // 1) fused: hebbdot plain stream (L3-allocating) + scalar split-K GEMM
    k_dot_gates<<<NGEMM + B_ * NCH, 256, 0, stream>>>(
        hebb, h0, inputs,
        Wxf, Whf, Wxi, Whi, Wxo, Who, Wxc, w, pre, part);
    // 2) finalize + update merged (reverse slabs, batched loads, NT stores)
    k_updatev<<<2048, 256, 0, stream>>>(
        hebb, h0, pre, part, c0, alpha,
        bxf, bhf, bxi, bhi, bxo, bho, bxc,
        Wmod, bmod, Wfan, bfan, out);
}